// Round 1
// baseline (36.383 us; speedup 1.0000x reference)
//
#include <hip/hip_runtime.h>
#include <hip/hip_bf16.h>

// Reference collapses: softmax over singleton axis==1 -> attention weights == 1,
// so ctx[b,h] = sum_l fmap[b,l,h] (independent of LSTM/t), hiddens[b,t,:] = ctx[b,:],
// out[b,t,c] = dot(ctx[b,:], W_gen[c,:]) + b_gen[c]  (broadcast over t).
// LSTM / embedding / text are dead code.

constexpr int Hd = 512;   // hidden
constexpr int Cd = 4096;  // classes
constexpr int Bd = 64;    // batch
constexpr int Td = 32;    // timesteps
constexpr int Ld = 256;   // FH*FW spatial positions

// K1: ctx[b*Hd + h] = sum over 256 contiguous floats of origin_fmap[b][h][:][:]
// one wave per row; 64 lanes x float4 = 1KB row
__global__ __launch_bounds__(256) void reduce_rows(const float* __restrict__ in,
                                                   float* __restrict__ ctx) {
    const int gtid = blockIdx.x * 256 + threadIdx.x;
    const int row  = gtid >> 6;             // 0 .. 32767 (grid sized exactly)
    const int lane = threadIdx.x & 63;
    const float4 v = reinterpret_cast<const float4*>(in + (size_t)row * Ld)[lane];
    float s = v.x + v.y + v.z + v.w;
    #pragma unroll
    for (int m = 1; m < 64; m <<= 1)
        s += __shfl_xor(s, m, 64);
    if (lane == 0) ctx[row] = s;
}

// K2: out[b][t][c] = dot(ctx[b,:], Wgen[c,:]) + bgen[c], replicated over t.
// grid = (Cd/64, Bd/16) = (64, 4); block = 256 threads (4 waves).
// wave w handles b-subgroup of 4; lanes = 64 consecutive c.
__global__ __launch_bounds__(256) void gemm_bcast(const float* __restrict__ ctx,
                                                  const float* __restrict__ Wgen,
                                                  const float* __restrict__ bgen,
                                                  float* __restrict__ out) {
    __shared__ float xs[16][Hd];  // 16 ctx rows = 32 KB
    const int tid = threadIdx.x;
    const int b0  = blockIdx.y * 16;
    const int c   = blockIdx.x * 64 + (tid & 63);
    const int bl  = tid >> 6;     // wave id 0..3 -> b-subgroup

    // cooperative, coalesced load of 16 ctx rows (8192 floats = 2048 float4)
    {
        const float4* src = reinterpret_cast<const float4*>(ctx + (size_t)b0 * Hd);
        float4* dst = reinterpret_cast<float4*>(&xs[0][0]);
        #pragma unroll
        for (int i = 0; i < 8; ++i)
            dst[tid + 256 * i] = src[tid + 256 * i];
    }
    __syncthreads();

    const float4* w  = reinterpret_cast<const float4*>(Wgen + (size_t)c * Hd);
    const float4* x0 = reinterpret_cast<const float4*>(&xs[bl * 4 + 0][0]);
    const float4* x1 = reinterpret_cast<const float4*>(&xs[bl * 4 + 1][0]);
    const float4* x2 = reinterpret_cast<const float4*>(&xs[bl * 4 + 2][0]);
    const float4* x3 = reinterpret_cast<const float4*>(&xs[bl * 4 + 3][0]);

    float a0 = 0.f, a1 = 0.f, a2 = 0.f, a3 = 0.f;
    #pragma unroll 4
    for (int h = 0; h < Hd / 4; ++h) {
        const float4 wv = w[h];
        const float4 v0 = x0[h];
        const float4 v1 = x1[h];
        const float4 v2 = x2[h];
        const float4 v3 = x3[h];
        a0 += wv.x * v0.x + wv.y * v0.y + wv.z * v0.z + wv.w * v0.w;
        a1 += wv.x * v1.x + wv.y * v1.y + wv.z * v1.z + wv.w * v1.w;
        a2 += wv.x * v2.x + wv.y * v2.y + wv.z * v2.z + wv.w * v2.w;
        a3 += wv.x * v3.x + wv.y * v3.y + wv.z * v3.z + wv.w * v3.w;
    }
    const float bg = bgen[c];
    a0 += bg; a1 += bg; a2 += bg; a3 += bg;

    const int b = b0 + bl * 4;
    float* o = out + ((size_t)b * Td) * Cd + c;
    #pragma unroll
    for (int t = 0; t < Td; ++t) {
        o[(size_t)(0 * Td + t) * Cd] = a0;
        o[(size_t)(1 * Td + t) * Cd] = a1;
        o[(size_t)(2 * Td + t) * Cd] = a2;
        o[(size_t)(3 * Td + t) * Cd] = a3;
    }
}

extern "C" void kernel_launch(void* const* d_in, const int* in_sizes, int n_in,
                              void* d_out, int out_size, void* d_ws, size_t ws_size,
                              hipStream_t stream) {
    const float* fmap = (const float*)d_in[0];   // [64,512,8,32]
    const float* Wgen = (const float*)d_in[9];   // [4096,512]
    const float* bgen = (const float*)d_in[10];  // [4096]
    float* out = (float*)d_out;                  // [64,32,4096]
    float* ctx = (float*)d_ws;                   // [64,512] scratch (128 KB)

    // K1: 32768 rows, 4 rows (waves) per 256-thread block
    reduce_rows<<<dim3((Bd * Hd) / 4), dim3(256), 0, stream>>>(fmap, ctx);
    // K2: GEMM + broadcast write
    gemm_bcast<<<dim3(Cd / 64, Bd / 16), dim3(256), 0, stream>>>(ctx, Wgen, bgen, out);
}

// Round 2
// 27.247 us; speedup vs baseline: 1.3353x; 1.3353x over previous
//
#include <hip/hip_runtime.h>
#include <hip/hip_bf16.h>

// Reference collapses: softmax over singleton axis==1 -> attention weights == 1,
// so ctx[b,h] = sum_l fmap[b,l,h], out[b,t,c] = dot(ctx[b,:], W_gen[c,:]) + b_gen[c]
// broadcast over all t. LSTM / embedding / text are dead code.

constexpr int Hd = 512;   // hidden (K)
constexpr int Cd = 4096;  // classes (N)
constexpr int Bd = 64;    // batch (M)
constexpr int Td = 32;    // timesteps (broadcast)
constexpr int Ld = 256;   // FH*FW

// ---------------- K1: ctx[b*Hd+h] = sum of 256 contiguous floats ----------------
__global__ __launch_bounds__(256) void reduce_rows(const float* __restrict__ in,
                                                   float* __restrict__ ctx) {
    const int gtid = blockIdx.x * 256 + threadIdx.x;
    const int row  = gtid >> 6;
    const int lane = threadIdx.x & 63;
    const float4 v = reinterpret_cast<const float4*>(in + (size_t)row * Ld)[lane];
    float s = v.x + v.y + v.z + v.w;
    #pragma unroll
    for (int m = 1; m < 64; m <<= 1) s += __shfl_xor(s, m, 64);
    if (lane == 0) ctx[row] = s;
}

// all-DPP 16-lane rotate-add (row_ror:N); CTRL: 0x121|N-1 -> ror:1.. (0x128=ror8 etc.)
template<int CTRL>
__device__ __forceinline__ float ror_add(float v) {
    int r = __builtin_amdgcn_update_dpp(0, __float_as_int(v), CTRL, 0xF, 0xF, false);
    return v + __int_as_float(r);
}

// ---------------- K2: out[b][t][c] = ctx[b,:]·W[c,:] + bias, bcast over t -------
// grid (Cd/64=64 c-groups, Bd/4=16 b-groups), block 256 = 4 waves.
// wave w owns K-slice h in [w*128, w*128+128). lane = cpart*16 + hp:
//   cpart selects c within a c-quad, hp spans h (coalesced W reads, 256B segments).
// ctx held in registers (reused across all 16 c-quads). Cross-lane reduce via DPP,
// cross-wave reduce via 4KB LDS.
__global__ __launch_bounds__(256, 2) void gemm_bcast(const float* __restrict__ ctx,
                                                     const float* __restrict__ Wgen,
                                                     const float* __restrict__ bgen,
                                                     float* __restrict__ out) {
    __shared__ float part[4 * 64 * 4];  // [wave][c_local][b_local]
    const int tid   = threadIdx.x;
    const int w     = tid >> 6;     // K-slice
    const int lane  = tid & 63;
    const int cpart = lane >> 4;
    const int hp    = lane & 15;
    const int cblk  = blockIdx.x * 64;
    const int b0    = blockIdx.y * 4;

    const float4* W4 = reinterpret_cast<const float4*>(Wgen);
    const float4* X4 = reinterpret_cast<const float4*>(ctx);

    // ctx registers: xr[bb][j] = ctx[b0+bb][w*128 + j*64 + hp*4 .. +3]
    float4 xr[4][2];
    #pragma unroll
    for (int bb = 0; bb < 4; ++bb)
        #pragma unroll
        for (int j = 0; j < 2; ++j)
            xr[bb][j] = X4[(size_t)(b0 + bb) * 128 + w * 32 + j * 16 + hp];

    #pragma unroll 4
    for (int q = 0; q < 16; ++q) {
        const int c = cblk + q * 4 + cpart;
        const size_t base = (size_t)c * 128 + w * 32 + hp;
        const float4 w0 = W4[base];        // h = w*128 + hp*4
        const float4 w1 = W4[base + 16];   // h = w*128 + 64 + hp*4
        float acc[4];
        #pragma unroll
        for (int bb = 0; bb < 4; ++bb) {
            float a = w0.x * xr[bb][0].x + w0.y * xr[bb][0].y
                    + w0.z * xr[bb][0].z + w0.w * xr[bb][0].w
                    + w1.x * xr[bb][1].x + w1.y * xr[bb][1].y
                    + w1.z * xr[bb][1].z + w1.w * xr[bb][1].w;
            a = ror_add<0x128>(a);  // +ror8
            a = ror_add<0x124>(a);  // +ror4
            a = ror_add<0x122>(a);  // +ror2
            a = ror_add<0x121>(a);  // +ror1  -> full 16-lane sum in every lane
            acc[bb] = a;
        }
        if (hp == 0) {
            reinterpret_cast<float4*>(part)[w * 64 + (q * 4 + cpart)] =
                make_float4(acc[0], acc[1], acc[2], acc[3]);
        }
    }
    __syncthreads();

    const int cl = tid & 63;
    const int bl = tid >> 6;
    float v = part[(0 * 64 + cl) * 4 + bl] + part[(1 * 64 + cl) * 4 + bl]
            + part[(2 * 64 + cl) * 4 + bl] + part[(3 * 64 + cl) * 4 + bl]
            + bgen[cblk + cl];

    float* o = out + (size_t)(b0 + bl) * Td * Cd + cblk + cl;
    #pragma unroll
    for (int t = 0; t < Td; ++t) o[(size_t)t * Cd] = v;   // 256B-coalesced per wave
}

extern "C" void kernel_launch(void* const* d_in, const int* in_sizes, int n_in,
                              void* d_out, int out_size, void* d_ws, size_t ws_size,
                              hipStream_t stream) {
    const float* fmap = (const float*)d_in[0];   // [64,512,8,32]
    const float* Wgen = (const float*)d_in[9];   // [4096,512]
    const float* bgen = (const float*)d_in[10];  // [4096]
    float* out = (float*)d_out;                  // [64,32,4096]
    float* ctx = (float*)d_ws;                   // [64,512] scratch

    reduce_rows<<<dim3((Bd * Hd) / 4), dim3(256), 0, stream>>>(fmap, ctx);
    gemm_bcast<<<dim3(Cd / 64, Bd / 4), dim3(256), 0, stream>>>(ctx, Wgen, bgen, out);
}